// Round 4
// baseline (811.552 us; speedup 1.0000x reference)
//
#include <hip/hip_runtime.h>

#define NUM_B 256
#define SEQ_L 100
#define NPIX  240000
#define KPAD  1024
#define BN    128
#define BK    256
#define NWG   1875   // NPIX / BN

typedef __attribute__((ext_vector_type(8))) short short8;
typedef __attribute__((ext_vector_type(4))) float f32x4;

static __device__ __forceinline__ unsigned short f2bf(float f) {
  unsigned int u = __builtin_bit_cast(unsigned int, f);
  u += 0x7fffu + ((u >> 16) & 1u);   // round-to-nearest-even
  return (unsigned short)(u >> 16);
}

// ---------------- Kernel 1 (fused): embedding-bag means + fc1 + fc2 -> h2 bf16 [256][1024]
// 1024 threads (16 waves): 6-7 tokens/wave serial depth, 64 dot-groups for fc.
__global__ __launch_bounds__(1024) void embed_mlp_kernel(
    const int* __restrict__ bucket, const int* __restrict__ ids,
    const float* __restrict__ W100, const float* __restrict__ W10,
    const float* __restrict__ W0,
    const float* __restrict__ fc1_w, const float* __restrict__ fc1_b,
    const float* __restrict__ fc2_w, const float* __restrict__ fc2_b,
    unsigned short* __restrict__ h2out)
{
  __shared__ __align__(16) float xw[16][1000];  // per-wave partial sums (64 KB)
  __shared__ __align__(16) float xs[1000];
  __shared__ __align__(16) float h1s[200];
  __shared__ int sb[SEQ_L], sid[SEQ_L];
  __shared__ int cnt[16][3];
  __shared__ int cntT[3];

  const int row = blockIdx.x, tid = threadIdx.x;
  const int wid = tid >> 6, lane = tid & 63;

  if (tid < SEQ_L) {
    sb[tid]  = bucket[row * SEQ_L + tid];
    sid[tid] = ids[row * SEQ_L + tid];
  }
  __syncthreads();

  float acc0[8] = {0,0,0,0,0,0,0,0};
  float acc1[4] = {0,0,0,0};
  float acc2[4] = {0,0,0,0};
  int c0 = 0, c1 = 0, c2 = 0;

  for (int l = wid; l < SEQ_L; l += 16) {      // wave-uniform token
    const int b = sb[l];
    const long id = sid[l];
    if (b == 0) {
      ++c0; const float* r = W100 + id * 500;
      #pragma unroll
      for (int j = 0; j < 7; ++j) acc0[j] += r[lane + 64 * j];
      if (lane < 52) acc0[7] += r[lane + 448];
    } else if (b == 1) {
      ++c1; const float* r = W10 + id * 250;
      #pragma unroll
      for (int j = 0; j < 3; ++j) acc1[j] += r[lane + 64 * j];
      if (lane < 58) acc1[3] += r[lane + 192];
    } else {
      ++c2; const float* r = W0 + id * 250;
      #pragma unroll
      for (int j = 0; j < 3; ++j) acc2[j] += r[lane + 64 * j];
      if (lane < 58) acc2[3] += r[lane + 192];
    }
  }
  {
    float* xp = xw[wid];
    #pragma unroll
    for (int j = 0; j < 8; ++j) { int d = lane + 64 * j; if (d < 500) xp[d] = acc0[j]; }
    #pragma unroll
    for (int j = 0; j < 4; ++j) { int d = lane + 64 * j; if (d < 250) xp[500 + d] = acc1[j]; }
    #pragma unroll
    for (int j = 0; j < 4; ++j) { int d = lane + 64 * j; if (d < 250) xp[750 + d] = acc2[j]; }
    if (lane == 0) { cnt[wid][0] = c0; cnt[wid][1] = c1; cnt[wid][2] = c2; }
  }
  __syncthreads();
  if (tid < 3) { int s = 0; for (int w = 0; w < 16; ++w) s += cnt[w][tid]; cntT[tid] = s; }
  __syncthreads();
  if (tid < 1000) {
    float s = 0.f;
    #pragma unroll
    for (int w = 0; w < 16; ++w) s += xw[w][tid];
    const int bkt = tid < 500 ? 0 : (tid < 750 ? 1 : 2);
    const int c = cntT[bkt];
    xs[tid] = c ? s / (float)c : 0.f;
  }
  __syncthreads();

  const int g = tid >> 4, sl = tid & 15;       // 64 sixteen-lane groups

  for (int o = g; o < 200; o += 64) {
    const f32x4* wr = (const f32x4*)(fc1_w + o * 1000);
    const f32x4* xv = (const f32x4*)xs;
    float p = 0.f;
    for (int j = sl; j < 250; j += 16) {
      f32x4 a = xv[j], b = wr[j];
      p += a.x * b.x + a.y * b.y + a.z * b.z + a.w * b.w;
    }
    #pragma unroll
    for (int off = 8; off; off >>= 1) p += __shfl_down(p, off, 16);
    if (sl == 0) h1s[o] = fmaxf(p + fc1_b[o], 0.f);
  }
  __syncthreads();

  unsigned short* hrow = h2out + (long)row * KPAD;
  for (int o = g; o < 1000; o += 64) {
    const f32x4* wr = (const f32x4*)(fc2_w + o * 200);
    const f32x4* hv = (const f32x4*)h1s;
    float p = 0.f;
    #pragma unroll
    for (int j = sl; j < 50; j += 16) {
      f32x4 a = hv[j], b = wr[j];
      p += a.x * b.x + a.y * b.y + a.z * b.z + a.w * b.w;
    }
    #pragma unroll
    for (int off = 8; off; off >>= 1) p += __shfl_down(p, off, 16);
    if (sl == 0) hrow[o] = f2bf(fmaxf(p + fc2_b[o], 0.f));
  }
  if (tid < KPAD - 1000) hrow[1000 + tid] = 0;
}

// ---------------- Kernel 2: ratings = h2 @ out_w^T + out_b
// Producer/consumer: waves 4-7 stream out_w (1KB-run coalesced, fp32->bf16)
// into double-buffered LDS (2x64KB); waves 0-3 do MFMA with A-fragments
// loaded directly from L2-resident h2. One barrier per k-tile.
__global__ __launch_bounds__(512) void out_gemm_kernel(
    const unsigned short* __restrict__ h2,  // [256][1024] bf16 bits
    const float* __restrict__ out_w,        // [240000][1000] fp32
    const float* __restrict__ out_b,        // [240000]
    float* __restrict__ out)                // [256][240000]
{
  __shared__ __align__(16) unsigned char Bs[131072];   // 2 x 64KB B buffers; reused as E

  const int tid = threadIdx.x;
  const int wid = tid >> 6, lane = tid & 63;
  const int lrow = lane & 15, lkg = lane >> 4;

  // bijective XCD swizzle (nwg=1875, q=234, r=3)
  const int q = NWG / 8, r = NWG % 8;
  const int xcd = blockIdx.x & 7, bidx = blockIdx.x >> 3;
  const int wg = (xcd < r ? xcd * (q + 1) : r * (q + 1) + (xcd - r) * q) + bidx;
  const long n0 = (long)wg * BN;

  const f32x4 fz = {0.f, 0.f, 0.f, 0.f};
  const bool producer = (wid >= 4);

  // ---- producer staging: 128 rows x 256 f32 (128KB fp32 -> 64KB bf16 LDS).
  // Per instruction: one wave = one full 1KB contiguous row-chunk.
  auto stage = [&](unsigned char* dst, int kt) {
    const int ptid = tid - 256;              // 0..255
    f32x4 b0[8], b1[8];
    auto issue8 = [&](f32x4* b, int j0) {
      #pragma unroll
      for (int j = 0; j < 8; ++j) {
        int c = ptid + 256 * (j0 + j);
        int rw = c >> 6, gg = c & 63;
        int k = kt * 256 + gg * 4;
        b[j] = (k < 1000)
          ? __builtin_nontemporal_load((const f32x4*)(out_w + (long)(n0 + rw) * 1000 + k))
          : fz;
      }
    };
    auto write8 = [&](f32x4* b, int j0) {
      #pragma unroll
      for (int j = 0; j < 8; ++j) {
        int c = ptid + 256 * (j0 + j);
        int rw = c >> 6, gg = c & 63;
        ushort4 h;
        h.x = f2bf(b[j].x); h.y = f2bf(b[j].y);
        h.z = f2bf(b[j].z); h.w = f2bf(b[j].w);
        *(ushort4*)(dst + rw * 512 + ((gg * 8) ^ ((rw & 7) << 4))) = h;
      }
    };
    issue8(b0, 0); issue8(b1, 8);
    write8(b0, 0); issue8(b0, 16);
    write8(b1, 8); issue8(b1, 24);
    write8(b0, 16); write8(b1, 24);
  };

  // ---- consumer state
  const int mh = (wid >> 1) & 1, cg = wid & 1;   // m-half, 64-col group
  const unsigned short* Am[8];
  #pragma unroll
  for (int m = 0; m < 8; ++m)
    Am[m] = h2 + (mh * 128 + m * 16 + lrow) * KPAD + lkg * 8;

  f32x4 acc[8][4];
  #pragma unroll
  for (int m = 0; m < 8; ++m)
    #pragma unroll
    for (int n = 0; n < 4; ++n) acc[m][n] = fz;

  auto compute = [&](const unsigned char* buf, int kt) {
    __builtin_amdgcn_s_setprio(1);
    #pragma unroll
    for (int kk = 0; kk < 8; ++kk) {
      short8 bf[4];
      #pragma unroll
      for (int n = 0; n < 4; ++n) {
        int nr = cg * 64 + n * 16 + lrow;
        bf[n] = *(const short8*)(buf + nr * 512 + (((kk * 64) + lkg * 16) ^ ((nr & 7) << 4)));
      }
      #pragma unroll
      for (int m = 0; m < 8; ++m) {
        short8 af = *(const short8*)(Am[m] + kt * 256 + kk * 32);
        #pragma unroll
        for (int n = 0; n < 4; ++n)
          acc[m][n] = __builtin_amdgcn_mfma_f32_16x16x32_bf16(af, bf[n], acc[m][n], 0, 0, 0);
      }
    }
    __builtin_amdgcn_s_setprio(0);
  };

  // ---- pipelined main loop (4 k-tiles)
  if (producer) stage(Bs, 0);
  __syncthreads();
  for (int kt = 0; kt < 4; ++kt) {
    if (producer) { if (kt < 3) stage(Bs + ((kt + 1) & 1) * 65536, kt + 1); }
    else          compute(Bs + (kt & 1) * 65536, kt);
    __syncthreads();
  }

  // ---- epilogue: stage 128x128 f32 halves in LDS, 512B-run NT stores
  float* E = (float*)Bs;             // [128][132] floats = 67,584 B
  float bias[4];
  if (!producer) {
    #pragma unroll
    for (int n = 0; n < 4; ++n) bias[n] = out_b[n0 + cg * 64 + n * 16 + lrow];
  }
  #pragma unroll
  for (int half = 0; half < 2; ++half) {
    if (!producer && mh == half) {
      #pragma unroll
      for (int m = 0; m < 8; ++m)
        #pragma unroll
        for (int n = 0; n < 4; ++n) {
          const int col = cg * 64 + n * 16 + lrow;
          #pragma unroll
          for (int rr = 0; rr < 4; ++rr) {
            const int rowl = m * 16 + lkg * 4 + rr;
            E[rowl * 132 + col] = acc[m][n][rr] + bias[n];
          }
        }
    }
    __syncthreads();
    const int rbase = half * 128;
    #pragma unroll
    for (int s = 0; s < 8; ++s) {
      const int rowl = s * 16 + (tid >> 5);
      const int c = (tid & 31) * 4;
      f32x4 v = *(const f32x4*)(E + rowl * 132 + c);
      __builtin_nontemporal_store(v, (f32x4*)(out + (long)(rbase + rowl) * NPIX + n0 + c));
    }
    __syncthreads();
  }
}

extern "C" void kernel_launch(void* const* d_in, const int* in_sizes, int n_in,
                              void* d_out, int out_size, void* d_ws, size_t ws_size,
                              hipStream_t stream) {
  const int*   bucket = (const int*)d_in[0];
  const int*   ids    = (const int*)d_in[1];
  const float* W100   = (const float*)d_in[2];
  const float* W10    = (const float*)d_in[3];
  const float* W0     = (const float*)d_in[4];
  const float* fc1w   = (const float*)d_in[5];
  const float* fc1b   = (const float*)d_in[6];
  const float* fc2w   = (const float*)d_in[7];
  const float* fc2b   = (const float*)d_in[8];
  const float* outw   = (const float*)d_in[9];
  const float* outb   = (const float*)d_in[10];
  float* out = (float*)d_out;
  unsigned short* h2w = (unsigned short*)d_ws;  // 256*1024*2B = 512 KB

  embed_mlp_kernel<<<NUM_B, 1024, 0, stream>>>(bucket, ids, W100, W10, W0,
                                               fc1w, fc1b, fc2w, fc2b, h2w);
  out_gemm_kernel<<<NWG, 512, 0, stream>>>(h2w, outw, outb, out);
}

// Round 5
// 548.764 us; speedup vs baseline: 1.4789x; 1.4789x over previous
//
#include <hip/hip_runtime.h>

#define NUM_B 256
#define SEQ_L 100
#define NPIX  240000
#define KPAD  1024
#define BN    128
#define BK    128
#define NWG   1875   // NPIX / BN

typedef __attribute__((ext_vector_type(8))) short short8;
typedef __attribute__((ext_vector_type(4))) float f32x4;

static __device__ __forceinline__ unsigned short f2bf(float f) {
  unsigned int u = __builtin_bit_cast(unsigned int, f);
  u += 0x7fffu + ((u >> 16) & 1u);   // round-to-nearest-even
  return (unsigned short)(u >> 16);
}

// ---------------- Kernel 1 (fused): embedding-bag means + fc1 + fc2 -> h2 bf16 [256][1024]
// 1024 threads (16 waves). Measured ~36 us in r4.
__global__ __launch_bounds__(1024) void embed_mlp_kernel(
    const int* __restrict__ bucket, const int* __restrict__ ids,
    const float* __restrict__ W100, const float* __restrict__ W10,
    const float* __restrict__ W0,
    const float* __restrict__ fc1_w, const float* __restrict__ fc1_b,
    const float* __restrict__ fc2_w, const float* __restrict__ fc2_b,
    unsigned short* __restrict__ h2out)
{
  __shared__ __align__(16) float xw[16][1000];  // per-wave partial sums (64 KB)
  __shared__ __align__(16) float xs[1000];
  __shared__ __align__(16) float h1s[200];
  __shared__ int sb[SEQ_L], sid[SEQ_L];
  __shared__ int cnt[16][3];
  __shared__ int cntT[3];

  const int row = blockIdx.x, tid = threadIdx.x;
  const int wid = tid >> 6, lane = tid & 63;

  if (tid < SEQ_L) {
    sb[tid]  = bucket[row * SEQ_L + tid];
    sid[tid] = ids[row * SEQ_L + tid];
  }
  __syncthreads();

  float acc0[8] = {0,0,0,0,0,0,0,0};
  float acc1[4] = {0,0,0,0};
  float acc2[4] = {0,0,0,0};
  int c0 = 0, c1 = 0, c2 = 0;

  for (int l = wid; l < SEQ_L; l += 16) {      // wave-uniform token
    const int b = sb[l];
    const long id = sid[l];
    if (b == 0) {
      ++c0; const float* r = W100 + id * 500;
      #pragma unroll
      for (int j = 0; j < 7; ++j) acc0[j] += r[lane + 64 * j];
      if (lane < 52) acc0[7] += r[lane + 448];
    } else if (b == 1) {
      ++c1; const float* r = W10 + id * 250;
      #pragma unroll
      for (int j = 0; j < 3; ++j) acc1[j] += r[lane + 64 * j];
      if (lane < 58) acc1[3] += r[lane + 192];
    } else {
      ++c2; const float* r = W0 + id * 250;
      #pragma unroll
      for (int j = 0; j < 3; ++j) acc2[j] += r[lane + 64 * j];
      if (lane < 58) acc2[3] += r[lane + 192];
    }
  }
  {
    float* xp = xw[wid];
    #pragma unroll
    for (int j = 0; j < 8; ++j) { int d = lane + 64 * j; if (d < 500) xp[d] = acc0[j]; }
    #pragma unroll
    for (int j = 0; j < 4; ++j) { int d = lane + 64 * j; if (d < 250) xp[500 + d] = acc1[j]; }
    #pragma unroll
    for (int j = 0; j < 4; ++j) { int d = lane + 64 * j; if (d < 250) xp[750 + d] = acc2[j]; }
    if (lane == 0) { cnt[wid][0] = c0; cnt[wid][1] = c1; cnt[wid][2] = c2; }
  }
  __syncthreads();
  if (tid < 3) { int s = 0; for (int w = 0; w < 16; ++w) s += cnt[w][tid]; cntT[tid] = s; }
  __syncthreads();
  if (tid < 1000) {
    float s = 0.f;
    #pragma unroll
    for (int w = 0; w < 16; ++w) s += xw[w][tid];
    const int bkt = tid < 500 ? 0 : (tid < 750 ? 1 : 2);
    const int c = cntT[bkt];
    xs[tid] = c ? s / (float)c : 0.f;
  }
  __syncthreads();

  const int g = tid >> 4, sl = tid & 15;       // 64 sixteen-lane groups

  for (int o = g; o < 200; o += 64) {
    const f32x4* wr = (const f32x4*)(fc1_w + o * 1000);
    const f32x4* xv = (const f32x4*)xs;
    float p = 0.f;
    for (int j = sl; j < 250; j += 16) {
      f32x4 a = xv[j], b = wr[j];
      p += a.x * b.x + a.y * b.y + a.z * b.z + a.w * b.w;
    }
    #pragma unroll
    for (int off = 8; off; off >>= 1) p += __shfl_down(p, off, 16);
    if (sl == 0) h1s[o] = fmaxf(p + fc1_b[o], 0.f);
  }
  __syncthreads();

  unsigned short* hrow = h2out + (long)row * KPAD;
  for (int o = g; o < 1000; o += 64) {
    const f32x4* wr = (const f32x4*)(fc2_w + o * 200);
    const f32x4* hv = (const f32x4*)h1s;
    float p = 0.f;
    #pragma unroll
    for (int j = sl; j < 50; j += 16) {
      f32x4 a = hv[j], b = wr[j];
      p += a.x * b.x + a.y * b.y + a.z * b.z + a.w * b.w;
    }
    #pragma unroll
    for (int off = 8; off; off >>= 1) p += __shfl_down(p, off, 16);
    if (sl == 0) hrow[o] = f2bf(fmaxf(p + fc2_b[o], 0.f));
  }
  if (tid < KPAD - 1000) hrow[1000 + tid] = 0;
}

// ---------------- Kernel 2: ratings = h2 @ out_w^T + out_b
// r3 structure (all 8 waves stage + compute, BM=256/BN=128/BK=128) with:
//  - 2-deep E/O register prefetch, counted-vmcnt queue [B(kt),A(kt)] batches
//  - regular (non-NT) epilogue stores via LDS transpose (512B runs)
__global__ __launch_bounds__(512) void out_gemm_kernel(
    const unsigned short* __restrict__ h2,  // [256][1024] bf16 bits
    const float* __restrict__ out_w,        // [240000][1000] fp32
    const float* __restrict__ out_b,        // [240000]
    float* __restrict__ out)                // [256][240000]
{
  __shared__ __align__(16) unsigned char lds[98304];   // 96 KB
  unsigned char* As = lds;             // [256 rows][256B] bf16, XOR-swizzled
  unsigned char* Bs = lds + 65536;     // [128 rows][256B] bf16, XOR-swizzled

  const int tid = threadIdx.x;

  // bijective XCD swizzle (nwg=1875, q=234, r=3)
  const int q = NWG / 8, r = NWG % 8;
  const int xcd = blockIdx.x & 7, bidx = blockIdx.x >> 3;
  const int wg = (xcd < r ? xcd * (q + 1) : r * (q + 1) + (xcd - r) * q) + bidx;
  const long n0 = (long)wg * BN;

  const f32x4 fz = {0.f, 0.f, 0.f, 0.f};

  uint4 aE[8], aO[8];
  f32x4 bE[8], bO[8];

  // B: 128 rows x 128 k fp32 = 64KB/kt. 32 lanes read 512B contiguous per row.
  auto loadB = [&](f32x4* bR, int kt) {
    #pragma unroll
    for (int i = 0; i < 8; ++i) {
      int c = tid + 512 * i;
      int n = c >> 5, qq = c & 31;
      int k = kt * BK + qq * 4;
      bR[i] = (k < 1000)
        ? __builtin_nontemporal_load((const f32x4*)(out_w + (long)(n0 + n) * 1000 + k))
        : fz;
    }
  };
  // A: 256 rows x 128 k bf16 = 64KB/kt (L2-resident h2).
  auto loadA = [&](uint4* aR, int kt) {
    #pragma unroll
    for (int i = 0; i < 8; ++i) {
      int c = tid + 512 * i;
      int rw = c >> 4, k16 = c & 15;
      aR[i] = *(const uint4*)(h2 + rw * KPAD + kt * BK + k16 * 8);
    }
  };
  auto storeA = [&](uint4* aR) {
    #pragma unroll
    for (int i = 0; i < 8; ++i) {
      int c = tid + 512 * i;
      int rw = c >> 4, k16 = c & 15;
      *(uint4*)(As + rw * 256 + ((k16 * 16) ^ ((rw & 7) << 4))) = aR[i];
    }
  };
  auto storeB = [&](f32x4* bR) {
    #pragma unroll
    for (int i = 0; i < 8; ++i) {
      int c = tid + 512 * i;
      int n = c >> 5, qq = c & 31;
      ushort4 h;
      h.x = f2bf(bR[i].x); h.y = f2bf(bR[i].y);
      h.z = f2bf(bR[i].z); h.w = f2bf(bR[i].w);
      *(ushort4*)(Bs + n * 256 + ((qq * 8) ^ ((n & 7) << 4))) = h;
    }
  };

  const int wid = tid >> 6, lane = tid & 63;
  const int wm = wid >> 2, wn = wid & 3;      // wave grid 2 (M) x 4 (N)
  const int lrow = lane & 15, lkg = lane >> 4;

  f32x4 acc[8][2];
  #pragma unroll
  for (int m = 0; m < 8; ++m) { acc[m][0] = fz; acc[m][1] = fz; }

  auto compute = [&]() {
    #pragma unroll
    for (int kk = 0; kk < 4; ++kk) {
      short8 bf[2];
      #pragma unroll
      for (int n = 0; n < 2; ++n) {
        int nr = wn * 32 + n * 16 + lrow;
        bf[n] = *(const short8*)(Bs + nr * 256 + (((kk * 64) + lkg * 16) ^ ((nr & 7) << 4)));
      }
      #pragma unroll
      for (int m = 0; m < 8; ++m) {
        int rr = wm * 128 + m * 16 + lrow;
        short8 af = *(const short8*)(As + rr * 256 + (((kk * 64) + lkg * 16) ^ ((rr & 7) << 4)));
        acc[m][0] = __builtin_amdgcn_mfma_f32_16x16x32_bf16(af, bf[0], acc[m][0], 0, 0, 0);
        acc[m][1] = __builtin_amdgcn_mfma_f32_16x16x32_bf16(af, bf[1], acc[m][1], 0, 0, 0);
      }
    }
  };

  // ---- 2-deep pipelined main loop (8 k-tiles), E/O register sets.
  // vmcnt queue per wave: [B(kt),A(kt)] then [B(kt+1),A(kt+1)]; store(kt)
  // waits only its own batch (counted), kt+1 stays in flight across barriers.
  loadB(bE, 0); loadA(aE, 0);
  loadB(bO, 1); loadA(aO, 1);
  #pragma unroll 1
  for (int i = 0; i < 4; ++i) {
    storeA(aE); storeB(bE);
    __syncthreads();
    if (i < 3) { loadB(bE, 2 * i + 2); loadA(aE, 2 * i + 2); }
    compute();
    __syncthreads();

    storeA(aO); storeB(bO);
    __syncthreads();
    if (i < 3) { loadB(bO, 2 * i + 3); loadA(aO, 2 * i + 3); }
    compute();
    __syncthreads();
  }

  // ---- epilogue: stage 128x128 f32 halves in LDS, 512B-run regular stores
  const float b0 = out_b[n0 + wn * 32 + lrow];
  const float b1 = out_b[n0 + wn * 32 + 16 + lrow];
  float* E = (float*)lds;            // [128][132] floats = 67,584 B
  #pragma unroll
  for (int half = 0; half < 2; ++half) {
    if (wm == half) {
      #pragma unroll
      for (int m = 0; m < 8; ++m) {
        #pragma unroll
        for (int n = 0; n < 2; ++n) {
          const int col = wn * 32 + n * 16 + lrow;
          const float bias = n ? b1 : b0;
          #pragma unroll
          for (int rr = 0; rr < 4; ++rr) {
            const int rowl = m * 16 + lkg * 4 + rr;
            E[rowl * 132 + col] = acc[m][n][rr] + bias;
          }
        }
      }
    }
    __syncthreads();
    const int rbase = half * 128;
    #pragma unroll
    for (int s = 0; s < 8; ++s) {
      const int rowl = s * 16 + (tid >> 5);
      const int c = (tid & 31) * 4;
      f32x4 v = *(const f32x4*)(E + rowl * 132 + c);
      *(f32x4*)(out + (long)(rbase + rowl) * NPIX + n0 + c) = v;
    }
    __syncthreads();
  }
}

extern "C" void kernel_launch(void* const* d_in, const int* in_sizes, int n_in,
                              void* d_out, int out_size, void* d_ws, size_t ws_size,
                              hipStream_t stream) {
  const int*   bucket = (const int*)d_in[0];
  const int*   ids    = (const int*)d_in[1];
  const float* W100   = (const float*)d_in[2];
  const float* W10    = (const float*)d_in[3];
  const float* W0     = (const float*)d_in[4];
  const float* fc1w   = (const float*)d_in[5];
  const float* fc1b   = (const float*)d_in[6];
  const float* fc2w   = (const float*)d_in[7];
  const float* fc2b   = (const float*)d_in[8];
  const float* outw   = (const float*)d_in[9];
  const float* outb   = (const float*)d_in[10];
  float* out = (float*)d_out;
  unsigned short* h2w = (unsigned short*)d_ws;  // 256*1024*2B = 512 KB

  embed_mlp_kernel<<<NUM_B, 1024, 0, stream>>>(bucket, ids, W100, W10, W0,
                                               fc1w, fc1b, fc2w, fc2b, h2w);
  out_gemm_kernel<<<NWG, 512, 0, stream>>>(h2w, outw, outb, out);
}